// Round 1
// baseline (274.035 us; speedup 1.0000x reference)
//
#include <hip/hip_runtime.h>

// Problem constants: B=4, SEQ=4096, D=64, BS=32, V=512, R=128, P=33024
#define Bn   4
#define SEQn 4096
#define Dn   64
#define BSn  32
#define Vn   512
#define Rn   128
#define PPB  8256   // p's per batch = R*(R+1)/2

// ---------------- Phase 1: scores[b][m][v] = sum_d q[b][m][d] * emb[b][v][d]
// Block tile: 64 m x 128 v, 256 threads, per-thread 8m x 4v register tile.
#define TM   64
#define TVb  128
#define QP   68    // q LDS leading dim  (64+4: keeps b128 16B-aligned)
#define EP   132   // emb LDS leading dim (128+4)

__global__ __launch_bounds__(256) void scores_kernel(
    const float* __restrict__ q, const float* __restrict__ emb,
    float* __restrict__ scores)
{
  __shared__ float sq[Dn * QP];   // [d][m]
  __shared__ float se[Dn * EP];   // [d][v]

  int bx   = blockIdx.x;
  int vblk = bx & 3;            // V/TVb = 4
  int bblk = (bx >> 2) & 3;     // B = 4
  int mblk = bx >> 4;           // SEQ/TM = 64
  int m0 = mblk * TM;
  int v0 = vblk * TVb;

  const float* qbase = q   + ((size_t)bblk * SEQn + m0) * Dn;
  const float* ebase = emb + ((size_t)bblk * Vn   + v0) * Dn;

  int t = threadIdx.x;
  for (int idx = t; idx < TM * Dn / 4; idx += 256) {
    int e = idx * 4;
    int m = e >> 6;
    int d = e & 63;
    float4 x = *(const float4*)(qbase + (size_t)m * Dn + d);
    sq[(d + 0) * QP + m] = x.x;
    sq[(d + 1) * QP + m] = x.y;
    sq[(d + 2) * QP + m] = x.z;
    sq[(d + 3) * QP + m] = x.w;
  }
  for (int idx = t; idx < TVb * Dn / 4; idx += 256) {
    int e = idx * 4;
    int v = e >> 6;
    int d = e & 63;
    float4 x = *(const float4*)(ebase + (size_t)v * Dn + d);
    se[(d + 0) * EP + v] = x.x;
    se[(d + 1) * EP + v] = x.y;
    se[(d + 2) * EP + v] = x.z;
    se[(d + 3) * EP + v] = x.w;
  }
  __syncthreads();

  int tx = t & 31;
  int ty = t >> 5;
  int ml = ty * 8;
  int vl = tx * 4;

  float acc[8][4];
#pragma unroll
  for (int r = 0; r < 8; ++r)
#pragma unroll
    for (int k = 0; k < 4; ++k) acc[r][k] = 0.0f;

#pragma unroll 4
  for (int d = 0; d < Dn; ++d) {
    float4 qa = *(const float4*)&sq[d * QP + ml];
    float4 qb = *(const float4*)&sq[d * QP + ml + 4];
    float4 ev = *(const float4*)&se[d * EP + vl];
    float qr[8] = {qa.x, qa.y, qa.z, qa.w, qb.x, qb.y, qb.z, qb.w};
    float ek[4] = {ev.x, ev.y, ev.z, ev.w};
#pragma unroll
    for (int r = 0; r < 8; ++r)
#pragma unroll
      for (int k = 0; k < 4; ++k) acc[r][k] += qr[r] * ek[k];
  }

  float* obase = scores + ((size_t)bblk * SEQn + m0) * Vn + v0;
#pragma unroll
  for (int r = 0; r < 8; ++r) {
    float4 st = {acc[r][0], acc[r][1], acc[r][2], acc[r][3]};
    *(float4*)(obase + (size_t)(ml + r) * Vn + vl) = st;
  }
}

// ---------------- Phase 2: gather via LDS slab, 512-thread blocks
// p = b*8256 + r*(r+1)/2 + c,  c in [0, r]
// GCHUNK=32: each block stages the (b,r) slab ONCE and serves up to 32 p's
// (was 16) -> block count 2304 -> 1280, slab re-stage traffic 144 -> 80 MiB,
// and half as many stage+barrier cycles per output byte.
// 512 threads: sub = tid>>8 picks which p of a pair -> 2 p's per iteration,
// 16 iterations split into two batches of 8 so iv registers stay bounded:
//   batch A int4s preloaded BEFORE the barrier (overlap slab staging),
//   batch B int4s issued right AFTER the barrier (hide under batch A math).
// LDS 64 KB -> 2 blocks/CU -> 16 waves/CU.
#define GCHUNK 32

__global__ __launch_bounds__(512, 4) void gather_kernel(
    const float* __restrict__ scores, const int* __restrict__ info,
    float* __restrict__ out)
{
  __shared__ float slab[BSn * Vn];   // 64 KB

  int cid = blockIdx.x;   // [0, 320)
  int b   = blockIdx.y;

  // group g covers rows 32g..32g+31, each with (g+1) chunks; start = 16g(g+1)
  int g = 0;
  while (16 * (g + 1) * (g + 2) <= cid) ++g;
  int local = cid - 16 * g * (g + 1);
  int rq    = local / (g + 1);
  int chunk = local - rq * (g + 1);
  int r     = 32 * g + rq;
  int np    = min(GCHUNK, (r + 1) - chunk * GCHUNK);
  size_t p0 = (size_t)b * PPB + ((size_t)r * (r + 1)) / 2 + (size_t)chunk * GCHUNK;

  int tid = threadIdx.x;
  int sub = tid >> 8;          // which p of the pair
  int t   = tid & 255;
  int rowoff = (t >> 3) << 9;  // i = t>>3 ; i*512

  const int4* info4 = (const int4*)info;
  float4*     out4  = (float4*)out;

  // batch A info preload — independent of slab, overlaps staging
  int4 ivA[8];
#pragma unroll
  for (int k = 0; k < 8; ++k) {
    int pp = 2 * k + sub;
    size_t p = p0 + (pp < np ? pp : 0);   // clamp keeps loads in-bounds
    ivA[k] = info4[p * 256 + t];
  }

  // stage slab: rows r*32 .. r*32+31, all 512 v
  {
    const float4* src = (const float4*)(scores + ((size_t)b * SEQn + (size_t)r * BSn) * Vn);
    float4* dst = (float4*)slab;
    for (int idx = tid; idx < BSn * Vn / 4; idx += 512) dst[idx] = src[idx];
  }
  __syncthreads();

  // batch B info loads issued immediately (latency hides under batch A math)
  int4 ivB[8];
  if (np > 16) {
#pragma unroll
    for (int k = 0; k < 8; ++k) {
      int pp = 16 + 2 * k + sub;
      size_t p = p0 + (pp < np ? pp : 0);
      ivB[k] = info4[p * 256 + t];
    }
  }

#pragma unroll
  for (int k = 0; k < 8; ++k) {
    int pp = 2 * k + sub;
    if (pp < np) {
      float4 o;
      o.x = slab[rowoff + ivA[k].x];
      o.y = slab[rowoff + ivA[k].y];
      o.z = slab[rowoff + ivA[k].z];
      o.w = slab[rowoff + ivA[k].w];
      out4[(p0 + pp) * 256 + t] = o;
    }
  }

  if (np > 16) {
#pragma unroll
    for (int k = 0; k < 8; ++k) {
      int pp = 16 + 2 * k + sub;
      if (pp < np) {
        float4 o;
        o.x = slab[rowoff + ivB[k].x];
        o.y = slab[rowoff + ivB[k].y];
        o.z = slab[rowoff + ivB[k].z];
        o.w = slab[rowoff + ivB[k].w];
        out4[(p0 + pp) * 256 + t] = o;
      }
    }
  }
}

extern "C" void kernel_launch(void* const* d_in, const int* in_sizes, int n_in,
                              void* d_out, int out_size, void* d_ws, size_t ws_size,
                              hipStream_t stream) {
  const float* q    = (const float*)d_in[0];
  const float* emb  = (const float*)d_in[1];
  const int*   info = (const int*)d_in[2];
  // d_in[3]/d_in[4] (idxs_batch/idxs_row) derivable from tril structure.

  float* scores = (float*)d_ws;   // B*SEQ*V*4 = 32 MiB
  float* out    = (float*)d_out;

  int gemm_blocks = (SEQn / TM) * Bn * (Vn / TVb);   // 1024
  scores_kernel<<<gemm_blocks, 256, 0, stream>>>(q, emb, scores);

  dim3 ggrid(320, Bn);   // sum_r ceil((r+1)/32) = 320 chunks per batch
  gather_kernel<<<ggrid, 512, 0, stream>>>(scores, info, out);
}

// Round 2
// 273.062 us; speedup vs baseline: 1.0036x; 1.0036x over previous
//
#include <hip/hip_runtime.h>

// Problem constants: B=4, SEQ=4096, D=64, BS=32, V=512, R=128, P=33024
#define Bn   4
#define SEQn 4096
#define Dn   64
#define BSn  32
#define Vn   512
#define Rn   128
#define PPB  8256   // p's per batch = R*(R+1)/2

// ---------------- Phase 1: scores[b][m][v] = sum_d q[b][m][d] * emb[b][v][d]
// Block tile: 64 m x 128 v, 256 threads, per-thread 8m x 4v register tile.
#define TM   64
#define TVb  128
#define QP   68    // q LDS leading dim  (64+4: keeps b128 16B-aligned)
#define EP   132   // emb LDS leading dim (128+4)

__global__ __launch_bounds__(256) void scores_kernel(
    const float* __restrict__ q, const float* __restrict__ emb,
    float* __restrict__ scores)
{
  __shared__ float sq[Dn * QP];   // [d][m]
  __shared__ float se[Dn * EP];   // [d][v]

  int bx   = blockIdx.x;
  int vblk = bx & 3;            // V/TVb = 4
  int bblk = (bx >> 2) & 3;     // B = 4
  int mblk = bx >> 4;           // SEQ/TM = 64
  int m0 = mblk * TM;
  int v0 = vblk * TVb;

  const float* qbase = q   + ((size_t)bblk * SEQn + m0) * Dn;
  const float* ebase = emb + ((size_t)bblk * Vn   + v0) * Dn;

  int t = threadIdx.x;
  for (int idx = t; idx < TM * Dn / 4; idx += 256) {
    int e = idx * 4;
    int m = e >> 6;
    int d = e & 63;
    float4 x = *(const float4*)(qbase + (size_t)m * Dn + d);
    sq[(d + 0) * QP + m] = x.x;
    sq[(d + 1) * QP + m] = x.y;
    sq[(d + 2) * QP + m] = x.z;
    sq[(d + 3) * QP + m] = x.w;
  }
  for (int idx = t; idx < TVb * Dn / 4; idx += 256) {
    int e = idx * 4;
    int v = e >> 6;
    int d = e & 63;
    float4 x = *(const float4*)(ebase + (size_t)v * Dn + d);
    se[(d + 0) * EP + v] = x.x;
    se[(d + 1) * EP + v] = x.y;
    se[(d + 2) * EP + v] = x.z;
    se[(d + 3) * EP + v] = x.w;
  }
  __syncthreads();

  int tx = t & 31;
  int ty = t >> 5;
  int ml = ty * 8;
  int vl = tx * 4;

  float acc[8][4];
#pragma unroll
  for (int r = 0; r < 8; ++r)
#pragma unroll
    for (int k = 0; k < 4; ++k) acc[r][k] = 0.0f;

#pragma unroll 4
  for (int d = 0; d < Dn; ++d) {
    float4 qa = *(const float4*)&sq[d * QP + ml];
    float4 qb = *(const float4*)&sq[d * QP + ml + 4];
    float4 ev = *(const float4*)&se[d * EP + vl];
    float qr[8] = {qa.x, qa.y, qa.z, qa.w, qb.x, qb.y, qb.z, qb.w};
    float ek[4] = {ev.x, ev.y, ev.z, ev.w};
#pragma unroll
    for (int r = 0; r < 8; ++r)
#pragma unroll
      for (int k = 0; k < 4; ++k) acc[r][k] += qr[r] * ek[k];
  }

  float* obase = scores + ((size_t)bblk * SEQn + m0) * Vn + v0;
#pragma unroll
  for (int r = 0; r < 8; ++r) {
    float4 st = {acc[r][0], acc[r][1], acc[r][2], acc[r][3]};
    *(float4*)(obase + (size_t)(ml + r) * Vn + vl) = st;
  }
}

// ---------------- Phase 2: gather via HALF-ROW LDS slab, 512-thread blocks
// p = b*8256 + r*(r+1)/2 + c,  c in [0, r]
// Key fact: output element [p][i][j] only needs slab row i, and thread
// t (=0..255 within a p) has i = t>>3 fixed. So a block can own HALF the
// rows (16 of 32 -> 32 KB LDS) and serve the matching half of each p's
// output; a sibling block owns the other half. HBM traffic unchanged
// (info/out halves are disjoint contiguous 2 KB segments).
// 32 KB LDS + 512 thr -> 4 blocks/CU -> 32 waves/CU (100% theoretical,
// was 2 blocks/16 waves at 64 KB). 2560 blocks, better tail balance.
// 512 threads = 4 p's per iteration (sub = tid>>7), 8 iterations; info
// int4s in two register batches: A before the barrier (overlaps staging),
// B right after (hides under batch-A gather math).
#define GCHUNK 32

__global__ __launch_bounds__(512, 8) void gather_kernel(
    const float* __restrict__ scores, const int* __restrict__ info,
    float* __restrict__ out)
{
  __shared__ float slab[16 * Vn];   // 32 KB: 16 rows of the (b,r) slab

  int cid  = blockIdx.x;   // [0, 640) = (chunk ccid, half h) interleaved
  int b    = blockIdx.y;
  int h    = cid & 1;      // which 16-row half
  int ccid = cid >> 1;     // [0, 320)

  // group g covers rows 32g..32g+31, each with (g+1) chunks; start = 16g(g+1)
  int g = 0;
  while (16 * (g + 1) * (g + 2) <= ccid) ++g;
  int local = ccid - 16 * g * (g + 1);
  int rq    = local / (g + 1);
  int chunk = local - rq * (g + 1);
  int r     = 32 * g + rq;
  int np    = min(GCHUNK, (r + 1) - chunk * GCHUNK);
  size_t p0 = (size_t)b * PPB + ((size_t)r * (r + 1)) / 2 + (size_t)chunk * GCHUNK;

  int tid = threadIdx.x;
  int sub = tid >> 7;          // which p of the quad (0..3)
  int t7  = tid & 127;         // position within the half: i_local = t7>>3
  int t   = h * 128 + t7;      // position within the full p (0..255)
  int rowoff = (t7 >> 3) << 9; // local row * 512

  const int4* info4 = (const int4*)info;
  float4*     out4  = (float4*)out;

  // batch A info preload (pp = 0..15) — independent of slab, overlaps staging
  int4 ivA[4];
#pragma unroll
  for (int k = 0; k < 4; ++k) {
    int pp = 4 * k + sub;
    size_t p = p0 + (pp < np ? pp : 0);   // clamp keeps loads in-bounds
    ivA[k] = info4[p * 256 + t];
  }

  // stage 16 rows: r*32 + h*16 .. +15, all 512 v  (2048 float4, 4 iters)
  {
    const float4* src = (const float4*)(scores +
        ((size_t)b * SEQn + (size_t)r * BSn + (size_t)h * 16) * Vn);
    float4* dst = (float4*)slab;
#pragma unroll
    for (int k = 0; k < 4; ++k) dst[tid + 512 * k] = src[tid + 512 * k];
  }
  __syncthreads();

  // batch B info loads (pp = 16..31) issued immediately, hide under batch A
  int4 ivB[4];
  if (np > 16) {
#pragma unroll
    for (int k = 0; k < 4; ++k) {
      int pp = 16 + 4 * k + sub;
      size_t p = p0 + (pp < np ? pp : 0);
      ivB[k] = info4[p * 256 + t];
    }
  }

#pragma unroll
  for (int k = 0; k < 4; ++k) {
    int pp = 4 * k + sub;
    if (pp < np) {
      float4 o;
      o.x = slab[rowoff + ivA[k].x];
      o.y = slab[rowoff + ivA[k].y];
      o.z = slab[rowoff + ivA[k].z];
      o.w = slab[rowoff + ivA[k].w];
      out4[(p0 + pp) * 256 + t] = o;
    }
  }

  if (np > 16) {
#pragma unroll
    for (int k = 0; k < 4; ++k) {
      int pp = 16 + 4 * k + sub;
      if (pp < np) {
        float4 o;
        o.x = slab[rowoff + ivB[k].x];
        o.y = slab[rowoff + ivB[k].y];
        o.z = slab[rowoff + ivB[k].z];
        o.w = slab[rowoff + ivB[k].w];
        out4[(p0 + pp) * 256 + t] = o;
      }
    }
  }
}

extern "C" void kernel_launch(void* const* d_in, const int* in_sizes, int n_in,
                              void* d_out, int out_size, void* d_ws, size_t ws_size,
                              hipStream_t stream) {
  const float* q    = (const float*)d_in[0];
  const float* emb  = (const float*)d_in[1];
  const int*   info = (const int*)d_in[2];
  // d_in[3]/d_in[4] (idxs_batch/idxs_row) derivable from tril structure.

  float* scores = (float*)d_ws;   // B*SEQ*V*4 = 32 MiB
  float* out    = (float*)d_out;

  int gemm_blocks = (SEQn / TM) * Bn * (Vn / TVb);   // 1024
  scores_kernel<<<gemm_blocks, 256, 0, stream>>>(q, emb, scores);

  dim3 ggrid(640, Bn);   // 320 chunks x 2 half-row blocks per batch
  gather_kernel<<<ggrid, 512, 0, stream>>>(scores, info, out);
}